// Round 21
// baseline (354.576 us; speedup 1.0000x reference)
//
#include <hip/hip_runtime.h>
#include <math.h>

constexpr int BB  = 32;
constexpr int SQL = 2048;
constexpr int SKL = 2048;
constexpr int DD  = 64;

using f32x4 = __attribute__((ext_vector_type(4))) float;
using bfrag = __attribute__((ext_vector_type(8))) short;   // 8 bf16 = 4 VGPR
typedef unsigned long long u64;

static __device__ __forceinline__ unsigned short f2bf(float x) {
    unsigned u = __float_as_uint(x);
    u = u + 0x7FFFu + ((u >> 16) & 1u);          // round-nearest-even
    return (unsigned short)(u >> 16);
}
static __device__ __forceinline__ float bf2f(unsigned short h) {
    return __uint_as_float((unsigned)h << 16);
}

// async global->LDS, 16 B per lane (wave-uniform base + lane*16 dest)
static __device__ __forceinline__ void gld16(const void* g, void* l) {
    __builtin_amdgcn_global_load_lds(
        (const __attribute__((address_space(1))) void*)(size_t)g,
        (__attribute__((address_space(3))) void*)(unsigned)(size_t)l,
        16, 0, 0);
}

// ---- prepass 1: mask int32 -> 1 bit/elem, natural col order (proven r8/r13)
__global__ __launch_bounds__(256) void compress_mask(
    const int* __restrict__ m, unsigned char* __restrict__ bm)
{
    const int t = threadIdx.x;
    const size_t g0 = (size_t)blockIdx.x * 1024 + t;
    const int4* mp = (const int4*)m;
    int4 a0 = mp[(g0)       * 2], a1 = mp[(g0)       * 2 + 1];
    int4 b0 = mp[(g0 + 256) * 2], b1 = mp[(g0 + 256) * 2 + 1];
    int4 c0 = mp[(g0 + 512) * 2], c1 = mp[(g0 + 512) * 2 + 1];
    int4 d0 = mp[(g0 + 768) * 2], d1 = mp[(g0 + 768) * 2 + 1];
#define PACK8(v0, v1)                                                         \
    (unsigned char)((v0.x != 0 ? 1u : 0u)  | (v0.y != 0 ? 2u : 0u)   |        \
                    (v0.z != 0 ? 4u : 0u)  | (v0.w != 0 ? 8u : 0u)   |        \
                    (v1.x != 0 ? 16u : 0u) | (v1.y != 0 ? 32u : 0u)  |        \
                    (v1.z != 0 ? 64u : 0u) | (v1.w != 0 ? 128u : 0u))
    bm[g0]       = PACK8(a0, a1);
    bm[g0 + 256] = PACK8(b0, b1);
    bm[g0 + 512] = PACK8(c0, c1);
    bm[g0 + 768] = PACK8(d0, d1);
#undef PACK8
}

// ---- prepass 2: k fp32 -> SINGLE-plane bf16 swizzled records (128 B/col).
// Per (b,c): 8 x 16B d-groups, group gi stored at 16*(gi ^ (c&7)).
__global__ __launch_bounds__(256) void split_k1(
    const float* __restrict__ k, unsigned char* __restrict__ kswz)
{
    const int i0 = blockIdx.x * blockDim.x + threadIdx.x;  // (b,c,g)
    const int g  = i0 & 7;
    const int c  = (i0 >> 3) & 2047;
    const int b  = i0 >> 14;
    const float* kp = k + ((size_t)(b * 2048 + c)) * DD + g * 8;
    bfrag h;
    #pragma unroll
    for (int j = 0; j < 8; ++j)
        h[j] = (short)f2bf(kp[j]);
    unsigned char* rec = kswz + ((size_t)(b * 2048 + c)) * 128;
    *(bfrag*)(rec + 16 * (g ^ (c & 7))) = h;
}

#define MF(A, B, C) __builtin_amdgcn_mfma_f32_16x16x32_bf16((A), (B), (C), 0, 0, 0)
#define NIB4(M) ((unsigned)((M).x ? 1u:0u) | ((M).y ? 2u:0u) |                 \
                 ((M).z ? 4u:0u) | ((M).w ? 8u:0u))

// ---- main: block = 8 waves (512 thr) = 32 q-rows x 2048 cols; wave w owns
// cols [w*256,(w+1)*256) = 16 tiles, computing TWO 16-row groups per tile
// (shared k frags -> half the k L2 traffic). TWO passes over k:
//   pass A: 8 MFMA/tile -> masked exp2 -> psum only (no score storage)
//   pass B: re-stage k from L2, recompute, store exp2(s)*rinv IN-LOOP
// -> stores stream uniformly instead of bursting at the end; sc[] gone.
// k via gld16 DMA depth-4 per-wave ring; store-aware counted-vmcnt ledgers.
template<bool PRE>
__global__ __launch_bounds__(512, 4) void sdpa_v21(
    const float* __restrict__ q, const float* __restrict__ k,
    const int* __restrict__ mask, const unsigned char* __restrict__ bm,
    const unsigned char* __restrict__ kswz, float* __restrict__ out)
{
    __shared__ char  kring[8][4][2048];    // 64 KB: per-wave depth-4 k ring
    __shared__ float s_red[8][2][16];      // 1 KB

    const int t   = threadIdx.x;
    const int l   = t & 63;
    const int w   = t >> 6;                    // 0..7
    const int lr  = l & 15;
    const int lg  = l >> 4;
    const int bid = blockIdx.x;
    const int swz = (bid & 7) * 256 + (bid >> 3);   // bijective XCD chunking
    const int b   = swz >> 6;                       // batch
    const int r0  = (swz & 63) * 32;                // q-row base (32 rows)
    const int c0  = w * 256;                        // wave's col base
    const size_t row0 = (size_t)b * SQL + (size_t)(r0 + lr);        // g0 row
    const size_t row1 = row0 + 16;                                  // g1 row

    // ---- bitmask: both rows x this wave's 256 cols (4 u64 each)
    u64 ba0 = 0, ba1 = 0, ba2 = 0, ba3 = 0;
    u64 bb0 = 0, bb1 = 0, bb2 = 0, bb3 = 0;
    if constexpr (PRE) {
        const ulonglong2* wa = (const ulonglong2*)(bm + row0 * (SKL / 8) + w * 32);
        const ulonglong2* wb = (const ulonglong2*)(bm + row1 * (SKL / 8) + w * 32);
        const ulonglong2 va0 = wa[0], va1 = wa[1];
        const ulonglong2 vb0 = wb[0], vb1 = wb[1];
        ba0 = va0.x; ba1 = va0.y; ba2 = va1.x; ba3 = va1.y;
        bb0 = vb0.x; bb1 = vb0.y; bb2 = vb1.x; bb3 = vb1.y;
    }

    // ---- q fragments for both row groups, scale (log2e/8) folded, hi/lo
    constexpr float QS = 0.18033688011112042f;      // 0.125 * log2(e)
    bfrag qh0a, ql0a, qh1a, ql1a;                   // group 0 (rows r0..+15)
    bfrag qh0b, ql0b, qh1b, ql1b;                   // group 1 (rows +16..31)
#define LOADQ(ROW, H0, L0, H1, L1)                                             \
    do {                                                                       \
        const float* _qp = q + (ROW) * DD + lg * 8;                            \
        const f32x4 _x0 = *(const f32x4*)_qp;                                  \
        const f32x4 _x1 = *(const f32x4*)(_qp + 4);                            \
        const f32x4 _y0 = *(const f32x4*)(_qp + 32);                           \
        const f32x4 _y1 = *(const f32x4*)(_qp + 36);                           \
        _Pragma("unroll")                                                      \
        for (int _j = 0; _j < 4; ++_j) {                                       \
            float _a = _x0[_j] * QS, _c = _x1[_j] * QS;                        \
            float _d = _y0[_j] * QS, _e = _y1[_j] * QS;                        \
            unsigned short _h;                                                 \
            _h = f2bf(_a); H0[_j]   = (short)_h; L0[_j]   = (short)f2bf(_a - bf2f(_h)); \
            _h = f2bf(_c); H0[_j+4] = (short)_h; L0[_j+4] = (short)f2bf(_c - bf2f(_h)); \
            _h = f2bf(_d); H1[_j]   = (short)_h; L1[_j]   = (short)f2bf(_d - bf2f(_h)); \
            _h = f2bf(_e); H1[_j+4] = (short)_h; L1[_j+4] = (short)f2bf(_e - bf2f(_h)); \
        }                                                                      \
    } while (0)
    LOADQ(row0, qh0a, ql0a, qh1a, ql1a);
    LOADQ(row1, qh0b, ql0b, qh1b, ql1b);
#undef LOADQ
    __builtin_amdgcn_sched_barrier(0);      // pin q/bits loads before stages

    const char*  ksrc = PRE ? (const char*)(kswz + ((size_t)b * SKL + c0) * 128) : nullptr;
    const float* kraw = PRE ? nullptr : k + (size_t)b * SKL * DD;
    const int*   mr0  = PRE ? nullptr : mask + row0 * SKL + c0 + lg * 4;
    const int*   mr1  = PRE ? nullptr : mask + row1 * SKL + c0 + lg * 4;
    char* kseg = &kring[w][0][0];
    float* op0 = out + row0 * SKL + c0 + lg * 4;
    float* op1 = out + row1 * SKL + c0 + lg * 4;

#define STAGE(T)                                                               \
    do {                                                                       \
        if constexpr (PRE) {                                                   \
            char* _kd = kseg + (((T) & 3) << 11);                              \
            const char* _ks = ksrc + (size_t)(T) * 2048;                       \
            gld16(_ks + l * 16,        _kd + l * 16);                          \
            gld16(_ks + 1024 + l * 16, _kd + 1024 + l * 16);                   \
        }                                                                      \
    } while (0)

// common per-iter body: k frags + 8 MFMA -> _s0/_s1, nibbles -> _n0/_n1
#define CORE(T, MW0, MW1)                                                      \
        bfrag _kh0, _kh1;                                                      \
        int4 _mva, _mvb;                                                       \
        if constexpr (PRE) {                                                   \
            const char* _c = kseg + (((T) & 3) << 11) + lr * 128;              \
            _kh0 = *(const bfrag*)(_c + 16 * (lg ^ (lr & 7)));                 \
            _kh1 = *(const bfrag*)(_c + 16 * ((4 | lg) ^ (lr & 7)));           \
            asm volatile("s_waitcnt lgkmcnt(0)" ::: "memory");                 \
            __builtin_amdgcn_sched_barrier(0);                                 \
            if constexpr ((T) + 3 < 16) STAGE((T) + 3);                        \
        } else {                                                               \
            const float* _kc = kraw + (size_t)(c0 + (T) * 16 + lr) * DD;       \
            const f32x4 _v0 = *(const f32x4*)(_kc + lg * 8);                   \
            const f32x4 _v1 = *(const f32x4*)(_kc + lg * 8 + 4);               \
            const f32x4 _v2 = *(const f32x4*)(_kc + 32 + lg * 8);              \
            const f32x4 _v3 = *(const f32x4*)(_kc + 36 + lg * 8);              \
            _Pragma("unroll")                                                  \
            for (int _j = 0; _j < 4; ++_j) {                                   \
                _kh0[_j]     = (short)f2bf(_v0[_j]);                           \
                _kh0[_j + 4] = (short)f2bf(_v1[_j]);                           \
                _kh1[_j]     = (short)f2bf(_v2[_j]);                           \
                _kh1[_j + 4] = (short)f2bf(_v3[_j]);                           \
            }                                                                  \
            _mva = *(const int4*)(mr0 + (T) * 16);                             \
            _mvb = *(const int4*)(mr1 + (T) * 16);                             \
        }                                                                      \
        f32x4 _h = {0.f,0.f,0.f,0.f}, _m = {0.f,0.f,0.f,0.f};                  \
        _h = MF(_kh0, qh0a, _h);  _m = MF(_kh0, ql0a, _m);                     \
        _h = MF(_kh1, qh1a, _h);  _m = MF(_kh1, ql1a, _m);                     \
        const f32x4 _s0 = _h + _m;                                             \
        f32x4 _h2 = {0.f,0.f,0.f,0.f}, _m2 = {0.f,0.f,0.f,0.f};                \
        _h2 = MF(_kh0, qh0b, _h2);  _m2 = MF(_kh0, ql0b, _m2);                 \
        _h2 = MF(_kh1, qh1b, _h2);  _m2 = MF(_kh1, ql1b, _m2);                 \
        const f32x4 _s1 = _h2 + _m2;                                           \
        unsigned _n0, _n1;                                                     \
        if constexpr (PRE) {                                                   \
            _n0 = (unsigned)((MW0) >> (((T) & 3) * 16 + lg * 4)) & 0xFu;       \
            _n1 = (unsigned)((MW1) >> (((T) & 3) * 16 + lg * 4)) & 0xFu;       \
        } else {                                                               \
            _n0 = NIB4(_mva); _n1 = NIB4(_mvb);                                \
        }

#define ITERA(T, VMC, MW0, MW1)                                                \
    do {                                                                       \
        if constexpr (PRE)                                                     \
            asm volatile("s_waitcnt vmcnt(" #VMC ")" ::: "memory");            \
        CORE(T, MW0, MW1)                                                      \
        psum0 += ((_n0 & 1u) ? exp2f(_s0[0]) : 0.f)                            \
               + ((_n0 & 2u) ? exp2f(_s0[1]) : 0.f)                            \
               + ((_n0 & 4u) ? exp2f(_s0[2]) : 0.f)                            \
               + ((_n0 & 8u) ? exp2f(_s0[3]) : 0.f);                           \
        psum1 += ((_n1 & 1u) ? exp2f(_s1[0]) : 0.f)                            \
               + ((_n1 & 2u) ? exp2f(_s1[1]) : 0.f)                            \
               + ((_n1 & 4u) ? exp2f(_s1[2]) : 0.f)                            \
               + ((_n1 & 8u) ? exp2f(_s1[3]) : 0.f);                           \
    } while (0)

#define ITERB(T, VMC, MW0, MW1)                                                \
    do {                                                                       \
        if constexpr (PRE)                                                     \
            asm volatile("s_waitcnt vmcnt(" #VMC ")" ::: "memory");            \
        CORE(T, MW0, MW1)                                                      \
        f32x4 _o0, _o1;                                                        \
        _o0[0] = (_n0 & 1u) ? exp2f(_s0[0]) * rinv0 : 0.f;                     \
        _o0[1] = (_n0 & 2u) ? exp2f(_s0[1]) * rinv0 : 0.f;                     \
        _o0[2] = (_n0 & 4u) ? exp2f(_s0[2]) * rinv0 : 0.f;                     \
        _o0[3] = (_n0 & 8u) ? exp2f(_s0[3]) * rinv0 : 0.f;                     \
        _o1[0] = (_n1 & 1u) ? exp2f(_s1[0]) * rinv1 : 0.f;                     \
        _o1[1] = (_n1 & 2u) ? exp2f(_s1[1]) * rinv1 : 0.f;                     \
        _o1[2] = (_n1 & 4u) ? exp2f(_s1[2]) * rinv1 : 0.f;                     \
        _o1[3] = (_n1 & 8u) ? exp2f(_s1[3]) * rinv1 : 0.f;                     \
        *(f32x4*)(op0 + (T) * 16) = _o0;                                       \
        *(f32x4*)(op1 + (T) * 16) = _o1;                                       \
    } while (0)

    // =================== PASS A (psum only) ===================
    STAGE(0);
    STAGE(1);
    STAGE(2);
    float psum0 = 0.f, psum1 = 0.f;

    // ledger: stages only (2 ops/group, depth-4): steady vmcnt(4);
    // last stage at T=12; tails: T=14 -> 2, T=15 -> 0.
    ITERA(0,  4, ba0, bb0); ITERA(1,  4, ba0, bb0);
    ITERA(2,  4, ba0, bb0); ITERA(3,  4, ba0, bb0);
    ITERA(4,  4, ba1, bb1); ITERA(5,  4, ba1, bb1);
    ITERA(6,  4, ba1, bb1); ITERA(7,  4, ba1, bb1);
    ITERA(8,  4, ba2, bb2); ITERA(9,  4, ba2, bb2);
    ITERA(10, 4, ba2, bb2); ITERA(11, 4, ba2, bb2);
    ITERA(12, 4, ba3, bb3); ITERA(13, 4, ba3, bb3);
    ITERA(14, 2, ba3, bb3); ITERA(15, 0, ba3, bb3);

    // ---- row sums: lanes {l, l^16, l^32, l^48} share each q-row
    psum0 += __shfl_xor(psum0, 16, 64);
    psum0 += __shfl_xor(psum0, 32, 64);
    psum1 += __shfl_xor(psum1, 16, 64);
    psum1 += __shfl_xor(psum1, 32, 64);
    if (l < 16) {
        s_red[w][0][lr] = psum0;
        s_red[w][1][lr] = psum1;
    }
    __syncthreads();
    float tot0 = 0.f, tot1 = 0.f;
    #pragma unroll
    for (int ww = 0; ww < 8; ++ww) {
        tot0 += s_red[ww][0][lr];
        tot1 += s_red[ww][1][lr];
    }
    const float rinv0 = 1.0f / tot0;
    const float rinv1 = 1.0f / tot1;
    __syncthreads();                       // (also fences before re-staging)

    // =================== PASS B (recompute + streamed stores) ===============
    STAGE(0);
    STAGE(1);
    STAGE(2);

    // Store-aware ledger (2 stores issued at the TOP of each iter T>=1, for
    // tile T-1, BEFORE the vmcnt wait; FIFO-derived):
    //   T0=4, T1=6, T2=8, T3..13=10, T14=8, T15=6; final stores after loop.
    ITERB(0,  4,  ba0, bb0); ITERB(1,  6,  ba0, bb0);
    ITERB(2,  8,  ba0, bb0); ITERB(3,  10, ba0, bb0);
    ITERB(4,  10, ba1, bb1); ITERB(5,  10, ba1, bb1);
    ITERB(6,  10, ba1, bb1); ITERB(7,  10, ba1, bb1);
    ITERB(8,  10, ba2, bb2); ITERB(9,  10, ba2, bb2);
    ITERB(10, 10, ba2, bb2); ITERB(11, 10, ba2, bb2);
    ITERB(12, 10, ba3, bb3); ITERB(13, 10, ba3, bb3);
    ITERB(14, 8,  ba3, bb3); ITERB(15, 6,  ba3, bb3);

#undef ITERB
#undef ITERA
#undef CORE
#undef STAGE
}

extern "C" void kernel_launch(void* const* d_in, const int* in_sizes, int n_in,
                              void* d_out, int out_size, void* d_ws, size_t ws_size,
                              hipStream_t stream) {
    const float* q    = (const float*)d_in[0];
    const float* k    = (const float*)d_in[1];
    const int*   mask = (const int*)d_in[2];
    float*       out  = (float*)d_out;

    const size_t BM_B = (size_t)BB * SQL * SKL / 8;   // 16.78 MB bitmask
    const size_t KS_B = (size_t)BB * SKL * 128;       // 8.39 MB k records

    dim3 grid(2048);    // 32 batches x 64 row-blocks, XCD-swizzled in-kernel

    if (ws_size >= BM_B + KS_B) {
        unsigned char* bmp = (unsigned char*)d_ws;
        unsigned char* ksp = (unsigned char*)d_ws + BM_B;
        compress_mask<<<16384, 256, 0, stream>>>(mask, bmp);
        split_k1<<<2048, 256, 0, stream>>>(k, ksp);
        sdpa_v21<true><<<grid, 512, 0, stream>>>(q, k, mask, bmp, ksp, out);
    } else {
        sdpa_v21<false><<<grid, 512, 0, stream>>>(q, k, mask, nullptr, nullptr, out);
    }
}

// Round 23
// 296.241 us; speedup vs baseline: 1.1969x; 1.1969x over previous
//
#include <hip/hip_runtime.h>
#include <math.h>

constexpr int BB  = 32;
constexpr int SQL = 2048;
constexpr int SKL = 2048;
constexpr int DD  = 64;

using f32x4 = __attribute__((ext_vector_type(4))) float;
using i32x4 = __attribute__((ext_vector_type(4))) int;     // clang vector (NT-ok)
using bfrag = __attribute__((ext_vector_type(8))) short;   // 8 bf16 = 4 VGPR
typedef unsigned long long u64;

static __device__ __forceinline__ unsigned short f2bf(float x) {
    unsigned u = __float_as_uint(x);
    u = u + 0x7FFFu + ((u >> 16) & 1u);          // round-nearest-even
    return (unsigned short)(u >> 16);
}
static __device__ __forceinline__ float bf2f(unsigned short h) {
    return __uint_as_float((unsigned)h << 16);
}

// async global->LDS, 16 B per lane (wave-uniform base + lane*16 dest)
static __device__ __forceinline__ void gld16(const void* g, void* l) {
    __builtin_amdgcn_global_load_lds(
        (const __attribute__((address_space(1))) void*)(size_t)g,
        (__attribute__((address_space(3))) void*)(unsigned)(size_t)l,
        16, 0, 0);
}

// ---- prepass 1: mask int32 -> 1 bit/elem, natural col order.
// NON-TEMPORAL loads/stores: this 512 MB read-once stream must not evict
// the k records / bitmask reuse set from L2.
__global__ __launch_bounds__(256) void compress_mask(
    const int* __restrict__ m, unsigned char* __restrict__ bm)
{
    const int t = threadIdx.x;
    const size_t g0 = (size_t)blockIdx.x * 1024 + t;
    const i32x4* mp = (const i32x4*)m;
    i32x4 a0 = __builtin_nontemporal_load(&mp[(g0)       * 2]);
    i32x4 a1 = __builtin_nontemporal_load(&mp[(g0)       * 2 + 1]);
    i32x4 b0 = __builtin_nontemporal_load(&mp[(g0 + 256) * 2]);
    i32x4 b1 = __builtin_nontemporal_load(&mp[(g0 + 256) * 2 + 1]);
    i32x4 c0 = __builtin_nontemporal_load(&mp[(g0 + 512) * 2]);
    i32x4 c1 = __builtin_nontemporal_load(&mp[(g0 + 512) * 2 + 1]);
    i32x4 d0 = __builtin_nontemporal_load(&mp[(g0 + 768) * 2]);
    i32x4 d1 = __builtin_nontemporal_load(&mp[(g0 + 768) * 2 + 1]);
#define PACK8(v0, v1)                                                         \
    (unsigned char)((v0[0] != 0 ? 1u : 0u)  | (v0[1] != 0 ? 2u : 0u)   |      \
                    (v0[2] != 0 ? 4u : 0u)  | (v0[3] != 0 ? 8u : 0u)   |      \
                    (v1[0] != 0 ? 16u : 0u) | (v1[1] != 0 ? 32u : 0u)  |      \
                    (v1[2] != 0 ? 64u : 0u) | (v1[3] != 0 ? 128u : 0u))
    __builtin_nontemporal_store(PACK8(a0, a1), &bm[g0]);
    __builtin_nontemporal_store(PACK8(b0, b1), &bm[g0 + 256]);
    __builtin_nontemporal_store(PACK8(c0, c1), &bm[g0 + 512]);
    __builtin_nontemporal_store(PACK8(d0, d1), &bm[g0 + 768]);
#undef PACK8
}

// ---- prepass 2: k fp32 -> SINGLE-plane bf16 swizzled records (128 B/col).
// Per (b,c): 8 x 16B d-groups, group gi stored at 16*(gi ^ (c&7)).
__global__ __launch_bounds__(256) void split_k1(
    const float* __restrict__ k, unsigned char* __restrict__ kswz)
{
    const int i0 = blockIdx.x * blockDim.x + threadIdx.x;  // (b,c,g)
    const int g  = i0 & 7;
    const int c  = (i0 >> 3) & 2047;
    const int b  = i0 >> 14;
    const float* kp = k + ((size_t)(b * 2048 + c)) * DD + g * 8;
    bfrag h;
    #pragma unroll
    for (int j = 0; j < 8; ++j)
        h[j] = (short)f2bf(kp[j]);
    unsigned char* rec = kswz + ((size_t)(b * 2048 + c)) * 128;
    *(bfrag*)(rec + 16 * (g ^ (c & 7))) = h;
}

#define MF(A, B, C) __builtin_amdgcn_mfma_f32_16x16x32_bf16((A), (B), (C), 0, 0, 0)
#define NIB4(M) ((unsigned)((M).x ? 1u:0u) | ((M).y ? 2u:0u) |                 \
                 ((M).z ? 4u:0u) | ((M).w ? 8u:0u))

// ---- main: block = 8 waves (512 thr) = 16 q-rows x 2048 cols; wave w owns
// cols [w*256,(w+1)*256) = 16 tiles. Single-plane k (s = qh·kh + ql·kh,
// 4 MFMA/tile), gld16 DMA depth-4 ring (2 KB/stage), steady vmcnt(4).
// Mask via bitmask prepass (4 u64/lane). LDS 66 KB -> 2 blocks/CU.
// Output stores are NON-TEMPORAL so the 537 MB write-once stream doesn't
// evict the k-record/bitmask reuse set from L2 (keeps k DMA at L2 latency).
template<bool PRE>
__global__ __launch_bounds__(512, 4) void sdpa_v22(
    const float* __restrict__ q, const float* __restrict__ k,
    const int* __restrict__ mask, const unsigned char* __restrict__ bm,
    const unsigned char* __restrict__ kswz, float* __restrict__ out)
{
    __shared__ char  kring[8][4][2048];    // 64 KB: per-wave depth-4 k ring
    __shared__ float s_red[8][16];         // 512 B

    const int t   = threadIdx.x;
    const int l   = t & 63;
    const int w   = t >> 6;                    // 0..7
    const int lr  = l & 15;
    const int lg  = l >> 4;
    const int bid = blockIdx.x;
    const int swz = (bid & 7) * 512 + (bid >> 3);   // bijective XCD chunking
    const int b   = swz >> 7;                       // batch
    const int r0  = (swz & 127) * 16;               // q-row base (16 rows)
    const int c0  = w * 256;                        // wave's col base
    const size_t rowg = (size_t)b * SQL + (size_t)(r0 + lr);

    // ---- bitmask: this lane's row x this wave's 256 cols (4 u64)
    u64 ba0 = 0, ba1 = 0, ba2 = 0, ba3 = 0;
    if constexpr (PRE) {
        const ulonglong2* wp = (const ulonglong2*)(bm + rowg * (SKL / 8) + w * 32);
        const ulonglong2 v0 = wp[0];
        const ulonglong2 v1 = wp[1];
        ba0 = v0.x; ba1 = v0.y; ba2 = v1.x; ba3 = v1.y;
    }

    // ---- q fragments, scale (log2e/8) folded, hi/lo split
    constexpr float QS = 0.18033688011112042f;      // 0.125 * log2(e)
    bfrag qh0, ql0, qh1, ql1;
    {
        const float* qp = q + rowg * DD + lg * 8;
        const f32x4 x0 = *(const f32x4*)qp;
        const f32x4 x1 = *(const f32x4*)(qp + 4);
        const f32x4 y0 = *(const f32x4*)(qp + 32);
        const f32x4 y1 = *(const f32x4*)(qp + 36);
        #pragma unroll
        for (int j = 0; j < 4; ++j) {
            float a = x0[j] * QS, c = x1[j] * QS;
            float d = y0[j] * QS, e = y1[j] * QS;
            unsigned short h;
            h = f2bf(a); qh0[j]     = (short)h; ql0[j]     = (short)f2bf(a - bf2f(h));
            h = f2bf(c); qh0[j + 4] = (short)h; ql0[j + 4] = (short)f2bf(c - bf2f(h));
            h = f2bf(d); qh1[j]     = (short)h; ql1[j]     = (short)f2bf(d - bf2f(h));
            h = f2bf(e); qh1[j + 4] = (short)h; ql1[j + 4] = (short)f2bf(e - bf2f(h));
        }
    }
    __builtin_amdgcn_sched_barrier(0);      // pin q/bits loads before stages

    const char*  ksrc = PRE ? (const char*)(kswz + ((size_t)b * SKL + c0) * 128) : nullptr;
    const float* kraw = PRE ? nullptr : k + (size_t)b * SKL * DD;
    const int*   mrp  = PRE ? nullptr : mask + rowg * SKL + c0 + lg * 4;
    char* kseg = &kring[w][0][0];

#define STAGE(T)                                                               \
    do {                                                                       \
        if constexpr (PRE) {                                                   \
            char* _kd = kseg + (((T) & 3) << 11);                              \
            const char* _ks = ksrc + (size_t)(T) * 2048;                       \
            gld16(_ks + l * 16,        _kd + l * 16);                          \
            gld16(_ks + 1024 + l * 16, _kd + 1024 + l * 16);                   \
        }                                                                      \
    } while (0)

    // ---- prologue: stages 0..2 in flight
    STAGE(0);
    STAGE(1);
    STAGE(2);

    unsigned sc[32];                  // packed bf16 exp: [tile][pair]
    float psum = 0.f;

#define ITER(T, VMC, MW)                                                       \
    do {                                                                       \
        bfrag _kh0, _kh1;                                                      \
        int4 _mv;                                                              \
        if constexpr (PRE) {                                                   \
            asm volatile("s_waitcnt vmcnt(" #VMC ")" ::: "memory");            \
            const char* _c = kseg + (((T) & 3) << 11) + lr * 128;              \
            _kh0 = *(const bfrag*)(_c + 16 * (lg ^ (lr & 7)));                 \
            _kh1 = *(const bfrag*)(_c + 16 * ((4 | lg) ^ (lr & 7)));           \
            asm volatile("s_waitcnt lgkmcnt(0)" ::: "memory");                 \
            __builtin_amdgcn_sched_barrier(0);                                 \
            if constexpr ((T) + 3 < 16) STAGE((T) + 3);                        \
        } else {                                                               \
            const float* _kc = kraw + (size_t)(c0 + (T) * 16 + lr) * DD;       \
            const f32x4 _v0 = *(const f32x4*)(_kc + lg * 8);                   \
            const f32x4 _v1 = *(const f32x4*)(_kc + lg * 8 + 4);               \
            const f32x4 _v2 = *(const f32x4*)(_kc + 32 + lg * 8);              \
            const f32x4 _v3 = *(const f32x4*)(_kc + 36 + lg * 8);              \
            _Pragma("unroll")                                                  \
            for (int _j = 0; _j < 4; ++_j) {                                   \
                _kh0[_j]     = (short)f2bf(_v0[_j]);                           \
                _kh0[_j + 4] = (short)f2bf(_v1[_j]);                           \
                _kh1[_j]     = (short)f2bf(_v2[_j]);                           \
                _kh1[_j + 4] = (short)f2bf(_v3[_j]);                           \
            }                                                                  \
            _mv = *(const int4*)(mrp + (T) * 16);                              \
        }                                                                      \
        /* hh chain + lo chain (2 indep accs, 4 MFMA) */                       \
        f32x4 _h = {0.f, 0.f, 0.f, 0.f};                                       \
        f32x4 _m = {0.f, 0.f, 0.f, 0.f};                                       \
        _h = MF(_kh0, qh0, _h);  _m = MF(_kh0, ql0, _m);                       \
        _h = MF(_kh1, qh1, _h);  _m = MF(_kh1, ql1, _m);                       \
        const f32x4 _s = _h + _m;                                              \
        unsigned _n;                                                           \
        if constexpr (PRE)                                                     \
            _n = (unsigned)((MW) >> (((T) & 3) * 16 + lg * 4)) & 0xFu;         \
        else                                                                   \
            _n = NIB4(_mv);                                                    \
        const float _e0 = (_n & 1u) ? exp2f(_s[0]) : 0.f;                      \
        const float _e1 = (_n & 2u) ? exp2f(_s[1]) : 0.f;                      \
        const float _e2 = (_n & 4u) ? exp2f(_s[2]) : 0.f;                      \
        const float _e3 = (_n & 8u) ? exp2f(_s[3]) : 0.f;                      \
        psum += (_e0 + _e1) + (_e2 + _e3);                                     \
        asm volatile("v_cvt_pk_bf16_f32 %0, %1, %2"                            \
                     : "=v"(sc[2 * (T)])     : "v"(_e0), "v"(_e1));            \
        asm volatile("v_cvt_pk_bf16_f32 %0, %1, %2"                            \
                     : "=v"(sc[2 * (T) + 1]) : "v"(_e2), "v"(_e3));            \
    } while (0)

    // ledger (issue-after-wait): at ITER(T) the two newer groups (T+1,T+2)
    // are outstanding = 4 ops -> vmcnt(4). Last stage issued at T=12;
    // tails: T=14 -> 2, T=15 -> 0.
    ITER(0,  4, ba0); ITER(1,  4, ba0); ITER(2,  4, ba0); ITER(3,  4, ba0);
    ITER(4,  4, ba1); ITER(5,  4, ba1); ITER(6,  4, ba1); ITER(7,  4, ba1);
    ITER(8,  4, ba2); ITER(9,  4, ba2); ITER(10, 4, ba2); ITER(11, 4, ba2);
    ITER(12, 4, ba3); ITER(13, 4, ba3); ITER(14, 2, ba3); ITER(15, 0, ba3);
#undef ITER
#undef STAGE

    // ---- row sums: lanes {l, l^16, l^32, l^48} share each q-row
    psum += __shfl_xor(psum, 16, 64);
    psum += __shfl_xor(psum, 32, 64);
    if (l < 16) s_red[w][lr] = psum;
    __syncthreads();

    float tot = 0.f;
    #pragma unroll
    for (int ww = 0; ww < 8; ++ww)
        tot += s_red[ww][lr];
    const float rinv = 1.0f / tot;

    // ---- unpack, normalize, NON-TEMPORAL float4 stores
    float* op = out + rowg * SKL + c0 + lg * 4;
    #pragma unroll
    for (int T = 0; T < 16; ++T) {
        const unsigned p01 = sc[2 * T];
        const unsigned p23 = sc[2 * T + 1];
        f32x4 o;
        o[0] = bf2f((unsigned short)(p01 & 0xffffu)) * rinv;
        o[1] = bf2f((unsigned short)(p01 >> 16))     * rinv;
        o[2] = bf2f((unsigned short)(p23 & 0xffffu)) * rinv;
        o[3] = bf2f((unsigned short)(p23 >> 16))     * rinv;
        __builtin_nontemporal_store(o, (f32x4*)(op + T * 16));
    }
}

extern "C" void kernel_launch(void* const* d_in, const int* in_sizes, int n_in,
                              void* d_out, int out_size, void* d_ws, size_t ws_size,
                              hipStream_t stream) {
    const float* q    = (const float*)d_in[0];
    const float* k    = (const float*)d_in[1];
    const int*   mask = (const int*)d_in[2];
    float*       out  = (float*)d_out;

    const size_t BM_B = (size_t)BB * SQL * SKL / 8;   // 16.78 MB bitmask
    const size_t KS_B = (size_t)BB * SKL * 128;       // 8.39 MB k records

    dim3 grid(4096);    // 32 batches x 128 row-blocks, XCD-swizzled in-kernel

    if (ws_size >= BM_B + KS_B) {
        unsigned char* bmp = (unsigned char*)d_ws;
        unsigned char* ksp = (unsigned char*)d_ws + BM_B;
        compress_mask<<<16384, 256, 0, stream>>>(mask, bmp);
        split_k1<<<2048, 256, 0, stream>>>(k, ksp);
        sdpa_v22<true><<<grid, 512, 0, stream>>>(q, k, mask, bmp, ksp, out);
    } else {
        sdpa_v22<false><<<grid, 512, 0, stream>>>(q, k, mask, nullptr, nullptr, out);
    }
}